// Round 5
// baseline (789.525 us; speedup 1.0000x reference)
//
#include <hip/hip_runtime.h>
#include <math.h>

#define D 512
#define S 128
#define NB 256   // N = A*B
#define T132 132 // S + L - 1

typedef short s16x8 __attribute__((ext_vector_type(8)));   // 8 bf16 (4 VGPRs)
typedef float f32x4 __attribute__((ext_vector_type(4)));
typedef unsigned short ushort;

static inline __device__ float4 ld4(const float* p) { return *(const float4*)p; }
static inline __device__ float4 ld4s(const float* p) { return *(const float4*)p; }
static inline __device__ float2 ld2s(const float* p) { return *(const float2*)p; }

// async global->LDS, 16B per lane; lp must be wave-uniform base, lane l lands at lp + 16*l
#define GLOAD_LDS16(gp, lp) __builtin_amdgcn_global_load_lds( \
    (const __attribute__((address_space(1))) unsigned int*)(const void*)(gp), \
    (__attribute__((address_space(3))) unsigned int*)(void*)(lp), 16, 0, 0)

static inline __device__ ushort bf16_rtn(float f) {
    unsigned u = __float_as_uint(f);
    unsigned r = u + 0x7FFFu + ((u >> 16) & 1u);
    return (ushort)(r >> 16);
}

// v_cvt_pk_bf16_f32: src0 -> low 16, src1 -> high 16 (pk family convention)
static inline __device__ unsigned pk_bf16(float a, float b) {
    unsigned r;
    asm("v_cvt_pk_bf16_f32 %0, %1, %2" : "=v"(r) : "v"(a), "v"(b));
    return r;
}

// 8 fp32 -> hi/lo bf16 fragments (RNE hi, RNE residual lo); ~24 VALU ops.
static inline __device__ void split_frag(float4 a0, float4 a1, s16x8& h, s16x8& l) {
    float f[8] = {a0.x,a0.y,a0.z,a0.w,a1.x,a1.y,a1.z,a1.w};
    union U { unsigned u[4]; s16x8 v; } hu, lu;
#pragma unroll
    for (int p = 0; p < 4; ++p) {
        unsigned u = pk_bf16(f[2*p], f[2*p+1]);
        float h0 = __uint_as_float(u << 16);
        float h1 = __uint_as_float(u & 0xffff0000u);
        hu.u[p] = u;
        lu.u[p] = pk_bf16(f[2*p] - h0, f[2*p+1] - h1);
    }
    h = hu.v;
    l = lu.v;
}

// ---------------------------------------------------------------------------
// Split fp32 rows into bf16 hi/lo (now only used for the 512x512 weights).
// grid.x = rows/4, block 256.
// ---------------------------------------------------------------------------
__global__ __launch_bounds__(256) void split_rows(
    const float* __restrict__ x, const float* __restrict__ pad,
    ushort* __restrict__ hi, ushort* __restrict__ lo,
    int rowsPerN, int padRows)
{
    int id  = blockIdx.x * 256 + threadIdx.x;
    int row = id >> 6, c8 = (id & 63) * 8;
    int n = row / rowsPerN, r = row - n * rowsPerN;
    const float* src = (r < padRows)
        ? (pad + ((size_t)(n * padRows + r)) * D + c8)
        : (x   + ((size_t)(n * (rowsPerN - padRows) + (r - padRows))) * D + c8);
    float4 f0 = ld4(src), f1 = ld4(src + 4);
    float v[8] = {f0.x,f0.y,f0.z,f0.w,f1.x,f1.y,f1.z,f1.w};
    ushort h[8], l[8];
#pragma unroll
    for (int i = 0; i < 8; ++i) {
        h[i] = bf16_rtn(v[i]);
        float hf = __uint_as_float(((unsigned)h[i]) << 16);
        l[i] = bf16_rtn(v[i] - hf);
    }
    size_t o = (size_t)row * D + c8;
#pragma unroll
    for (int i = 0; i < 4; ++i) {
        ((ushort2*)(hi + o))[i] = make_ushort2(h[2*i], h[2*i+1]);
        ((ushort2*)(lo + o))[i] = make_ushort2(l[2*i], l[2*i+1]);
    }
}

// ---------------------------------------------------------------------------
// Fused split-bf16 MFMA GEMM, double-buffered with COUNTED vmcnt (T3+T4):
// out[m][o] = sum_d A[m][d]*W[o][d] + bias[o].
// A is fp32 (optional per-n leading pad rows); staged fp32 via
// global_load_lds, split to bf16 hi/lo in-kernel (v_cvt_pk_bf16_f32) at
// fragment-read time. W pre-split bf16 hi/lo. 3 MFMA terms: hh + hl + lh.
// Tile 128x128, BK=32, 256 thr = 4 waves (2x2), each wave 64x64 via 4x4
// mfma_f32_16x16x32_bf16.
// LDS 64KB = 2 buffers x 32KB. Per buffer (ushort offsets, +bo):
//   A fp32 16 chunks [0,8192), Whi [8192,12288), Wlo [12288,16384).
// K-loop (steady state): STAGE(next tile, 8 loads/wave) -> s_waitcnt
// vmcnt(8) (waits ONLY the previous tile's 8 loads; next tile's stay in
// flight across the barrier) -> s_barrier -> compute -> s_barrier.
// vmcnt never drains to 0 in the main loop (AITER/T4 pattern).
// grid: (M/128, 4). M multiple of 128. K = N = 512.
// ---------------------------------------------------------------------------
__global__ __launch_bounds__(256, 2) void gemm_mfma_fused(
    const float* __restrict__ A, const float* __restrict__ pad,
    const ushort* __restrict__ Whi, const ushort* __restrict__ Wlo,
    const float* __restrict__ bias, float* __restrict__ out,
    int rowsPerN, int padRows)
{
    __shared__ ushort lds[32768];   // 64 KB, two 32 KB buffers
    const int t = threadIdx.x;
    const int wave = t >> 6, lane = t & 63;
    const int wm = wave >> 1, wn = wave & 1;
    const int blockRow = blockIdx.x * 128;
    const int blockCol = blockIdx.y * 128;
    const int lr = lane & 15, lg = lane >> 4;

    // ---- staging source pointers (computed once; +k0 per iteration) ----
    const float* rowPtr[4] = {nullptr, nullptr, nullptr, nullptr};
    const ushort* wPtr = nullptr;
    if (wave < 2) {
#pragma unroll
        for (int st = 0; st < 4; ++st) {
            int row = blockRow + (wave * 4 + st) * 16 + lr;
            const float* p;
            if (padRows > 0) {
                int n = row / rowsPerN, r = row - n * rowsPerN;
                p = (r < padRows)
                    ? pad + ((size_t)(n * padRows + r)) * D
                    : A   + ((size_t)(n * (rowsPerN - padRows) + (r - padRows))) * D;
            } else {
                p = A + (size_t)row * D;
            }
            rowPtr[st] = p + lg * 8;
        }
    } else {
        const ushort* wsrc = (wave == 2) ? Whi : Wlo;
        wPtr = wsrc + (size_t)(blockCol + lr) * 512 + lg * 8;
    }

    // stage one BK=32 slice into buffer at ushort-offset bo: 8 loads/wave
    auto STAGE = [&](int bo, int k0) {
        if (wave < 2) {
#pragma unroll
            for (int st = 0; st < 4; ++st) {
                GLOAD_LDS16(rowPtr[st] + k0,     &lds[bo + ((wave*4 + st)*2 + 0) * 512]);
                GLOAD_LDS16(rowPtr[st] + k0 + 4, &lds[bo + ((wave*4 + st)*2 + 1) * 512]);
            }
        } else {
            const int base = bo + 8192 + (wave - 2) * 4096;
#pragma unroll
            for (int st = 0; st < 8; ++st)
                GLOAD_LDS16(wPtr + (size_t)st * 16 * 512 + k0, &lds[base + st * 512]);
        }
    };

    f32x4 acc[4][4];
#pragma unroll
    for (int i = 0; i < 4; ++i)
#pragma unroll
        for (int j = 0; j < 4; ++j) acc[i][j] = (f32x4){0.f,0.f,0.f,0.f};

    // prologue: fill buffer 0 (8 loads/wave in flight)
    STAGE(0, 0);

    int bo = 0;
    for (int k0 = 0; k0 < 512; k0 += 32) {
        if (k0 + 32 < 512) {
            // issue NEXT tile (outstanding -> 16), then wait until only the
            // 8 just-issued remain: current tile's loads are complete.
            STAGE(bo ^ 16384, k0 + 32);
            asm volatile("s_waitcnt vmcnt(8)" ::: "memory");
        } else {
            asm volatile("s_waitcnt vmcnt(0)" ::: "memory");
        }
        asm volatile("s_barrier" ::: "memory");

        // compute from current buffer
        const float* Af = (const float*)&lds[bo];
        s16x8 bh[4], bl[4];
#pragma unroll
        for (int j = 0; j < 4; ++j) {
            bh[j] = *(const s16x8*)&lds[bo +  8192 + (wn*4 + j) * 512 + lane * 8];
            bl[j] = *(const s16x8*)&lds[bo + 12288 + (wn*4 + j) * 512 + lane * 8];
        }
#pragma unroll
        for (int i = 0; i < 4; ++i) {
            float4 a0 = *(const float4*)&Af[((wm*4 + i)*2 + 0) * 256 + lane * 4];
            float4 a1 = *(const float4*)&Af[((wm*4 + i)*2 + 1) * 256 + lane * 4];
            s16x8 ah, al;
            split_frag(a0, a1, ah, al);
#pragma unroll
            for (int j = 0; j < 4; ++j) {
                acc[i][j] = __builtin_amdgcn_mfma_f32_16x16x32_bf16(ah, bh[j], acc[i][j], 0, 0, 0);
                acc[i][j] = __builtin_amdgcn_mfma_f32_16x16x32_bf16(ah, bl[j], acc[i][j], 0, 0, 0);
                acc[i][j] = __builtin_amdgcn_mfma_f32_16x16x32_bf16(al, bh[j], acc[i][j], 0, 0, 0);
            }
        }

        // all waves done READING buffer bo before anyone overwrites it next
        // iteration (prefetch into bo is issued after this barrier).
        asm volatile("s_barrier" ::: "memory");
        bo ^= 16384;
    }

    // epilogue: C/D layout col=lane&15, row=(lane>>4)*4+reg
#pragma unroll
    for (int j = 0; j < 4; ++j) {
        int col = blockCol + (wn * 4 + j) * 16 + lr;
        float bb = bias[col];
#pragma unroll
        for (int i = 0; i < 4; ++i) {
            int row0 = blockRow + (wm * 4 + i) * 16 + lg * 4;
#pragma unroll
            for (int r = 0; r < 4; ++r)
                out[(size_t)(row0 + r) * 512 + col] = acc[i][j][r] + bb;
        }
    }
}

// ---------------------------------------------------------------------------
// Window softmax weights: one wave per (n, s). y: [N][132][D].
// ---------------------------------------------------------------------------
__global__ __launch_bounds__(256) void win_weights(const float* __restrict__ y,
                                                   float* __restrict__ wbuf)
{
    int g = blockIdx.x * 256 + threadIdx.x;
    int wv = g >> 6, lane = g & 63;
    int n = wv >> 7, s = wv & 127;
    const float* base = y + ((size_t)(n * T132 + s)) * D;
    float4 c0 = ld4(base + 4*D + lane*4);
    float4 c1 = ld4(base + 4*D + 256 + lane*4);
    float sc[5];
#pragma unroll
    for (int j = 0; j < 5; ++j) {
        float4 a0 = ld4(base + j*D + lane*4);
        float4 a1 = ld4(base + j*D + 256 + lane*4);
        float p = c0.x*a0.x + c0.y*a0.y + c0.z*a0.z + c0.w*a0.w
                + c1.x*a1.x + c1.y*a1.y + c1.z*a1.z + c1.w*a1.w;
#pragma unroll
        for (int off = 1; off < 64; off <<= 1) p += __shfl_xor(p, off);
        sc[j] = p * 0.044194173824159216f;   // 1/sqrt(512)
    }
    if (lane == 0) {
        float mx = sc[0];
#pragma unroll
        for (int j = 1; j < 5; ++j) mx = fmaxf(mx, sc[j]);
        float e[5], sum = 0.f;
#pragma unroll
        for (int j = 0; j < 5; ++j) { e[j] = expf(sc[j] - mx); sum += e[j]; }
        float inv = 1.f / sum;
        float* wp = wbuf + ((size_t)(n * 128 + s)) * 5;
#pragma unroll
        for (int j = 0; j < 5; ++j) wp[j] = e[j] * inv;
    }
}

// ---------------------------------------------------------------------------
// Scrambled window combine (reference's reshape (S,L)->(L,S)):
// out[n,s2,:] = sum_{l2<5} w[n, f/5, f%5] * y[n, f/5 + f%5, :],  f = l2*128+s2
// ---------------------------------------------------------------------------
__global__ __launch_bounds__(256) void win_combine(const float* __restrict__ y,
                                                   const float* __restrict__ wbuf,
                                                   float* __restrict__ outq)
{
    int g = blockIdx.x * 256 + threadIdx.x;
    int wv = g >> 6, lane = g & 63;
    int n = wv >> 7, s2 = wv & 127;
    float4 a0 = {0,0,0,0}, a1 = {0,0,0,0};
#pragma unroll
    for (int l2 = 0; l2 < 5; ++l2) {
        int f = l2 * 128 + s2;
        int sidx = f / 5;
        int l = f - sidx * 5;
        float wt = wbuf[((size_t)(n * 128 + sidx)) * 5 + l];
        const float* r = y + ((size_t)(n * T132 + sidx + l)) * D;
        float4 v0 = ld4(r + lane*4), v1 = ld4(r + 256 + lane*4);
        a0.x += wt*v0.x; a0.y += wt*v0.y; a0.z += wt*v0.z; a0.w += wt*v0.w;
        a1.x += wt*v1.x; a1.y += wt*v1.y; a1.z += wt*v1.z; a1.w += wt*v1.w;
    }
    float* op = outq + ((size_t)(n * 128 + s2)) * D;
    *(float4*)(op + lane*4) = a0;
    *(float4*)(op + 256 + lane*4) = a1;
}

// ---------------------------------------------------------------------------
// Attention 1 (MFMA, split-bf16): one block per (n,h), 256 thr = 4 waves,
// each wave owns 32 q-rows. K and V^T staged in LDS as bf16 hi/lo fragment
// chunks. Q fragments global->reg. S = QK^T via 3-term split MFMA;
// softmax in registers; P via per-wave LDS transpose; X = PV split MFMA.
// LDS 64 KB -> 2 blocks/CU. x1 may alias v (V fully staged before write).
// ---------------------------------------------------------------------------
__global__ __launch_bounds__(256, 2) void attn1_kernel(const float* __restrict__ q,
                                                       const float* __restrict__ k,
                                                       const float* __restrict__ v,
                                                       float* __restrict__ x1)
{
    __shared__ ushort lds[32768];   // 64 KB

    const int n = blockIdx.x >> 3, h = blockIdx.x & 7;
    const int t = threadIdx.x;
    const int wv = t >> 6, lane = t & 63;
    const int lr = lane & 15, lg = lane >> 4;

    const float* qb = q + ((size_t)n * 128) * D + h * 64;
    const float* kb = k + ((size_t)n * 128) * D + h * 64;
    const float* vb = v + ((size_t)n * 128) * D + h * 64;

    // ---- stage K -> bf16 hi/lo chunks (rows = k-rows, cols = d) ----
#pragma unroll
    for (int it = 0; it < 4; ++it) {
        int slot = t + 256 * it;           // chunk*64 + lane-in-chunk
        int c = slot >> 6, cl = slot & 63;
        int row = (c >> 1) * 16 + (cl & 15);
        int kc  = (c & 1) * 32 + (cl >> 4) * 8;
        const float* src = kb + (size_t)row * D + kc;
        float4 f0 = ld4(src), f1 = ld4(src + 4);
        float vv[8] = {f0.x,f0.y,f0.z,f0.w,f1.x,f1.y,f1.z,f1.w};
        s16x8 hb, lb;
#pragma unroll
        for (int j = 0; j < 8; ++j) {
            ushort hu = bf16_rtn(vv[j]);
            hb[j] = (short)hu;
            lb[j] = (short)bf16_rtn(vv[j] - __uint_as_float(((unsigned)hu) << 16));
        }
        *(s16x8*)&lds[        c * 512 + cl * 8] = hb;
        *(s16x8*)&lds[ 8192 + c * 512 + cl * 8] = lb;
    }
    // ---- stage V^T -> bf16 hi/lo chunks (rows = d, cols = k-rows) ----
#pragma unroll
    for (int it = 0; it < 4; ++it) {
        int slot = t + 256 * it;
        int c = slot >> 6, cl = slot & 63;
        int d  = (c >> 2) * 16 + (cl & 15);
        int kr = (c & 3) * 32 + (cl >> 4) * 8;
        const float* src = vb + (size_t)kr * D + d;
        s16x8 hb, lb;
#pragma unroll
        for (int j = 0; j < 8; ++j) {
            float f = src[(size_t)j * D];
            ushort hu = bf16_rtn(f);
            hb[j] = (short)hu;
            lb[j] = (short)bf16_rtn(f - __uint_as_float(((unsigned)hu) << 16));
        }
        *(s16x8*)&lds[16384 + c * 512 + cl * 8] = hb;
        *(s16x8*)&lds[24576 + c * 512 + cl * 8] = lb;
    }
    // ---- Q fragments straight into registers ----
    s16x8 qh[2][2], ql[2][2];
#pragma unroll
    for (int mf = 0; mf < 2; ++mf)
#pragma unroll
        for (int ks = 0; ks < 2; ++ks) {
            const float* src = qb + (size_t)(wv*32 + mf*16 + lr) * D + ks*32 + lg*8;
            float4 f0 = ld4(src), f1 = ld4(src + 4);
            float vv[8] = {f0.x,f0.y,f0.z,f0.w,f1.x,f1.y,f1.z,f1.w};
#pragma unroll
            for (int j = 0; j < 8; ++j) {
                ushort hu = bf16_rtn(vv[j]);
                qh[mf][ks][j] = (short)hu;
                ql[mf][ks][j] = (short)bf16_rtn(vv[j] - __uint_as_float(((unsigned)hu) << 16));
            }
        }

    __syncthreads();

    // ---- S = Q K^T (3-term split): rows mf*16+lg*4+r, cols nf*16+lr ----
    f32x4 acc[2][8];
#pragma unroll
    for (int mf = 0; mf < 2; ++mf)
#pragma unroll
        for (int nf = 0; nf < 8; ++nf) acc[mf][nf] = (f32x4){0.f,0.f,0.f,0.f};

#pragma unroll
    for (int ks = 0; ks < 2; ++ks)
#pragma unroll
        for (int nf = 0; nf < 8; ++nf) {
            s16x8 kh = *(const s16x8*)&lds[       (nf*2 + ks) * 512 + lane * 8];
            s16x8 kl = *(const s16x8*)&lds[8192 + (nf*2 + ks) * 512 + lane * 8];
#pragma unroll
            for (int mf = 0; mf < 2; ++mf) {
                acc[mf][nf] = __builtin_amdgcn_mfma_f32_16x16x32_bf16(qh[mf][ks], kh, acc[mf][nf], 0, 0, 0);
                acc[mf][nf] = __builtin_amdgcn_mfma_f32_16x16x32_bf16(qh[mf][ks], kl, acc[mf][nf], 0, 0, 0);
                acc[mf][nf] = __builtin_amdgcn_mfma_f32_16x16x32_bf16(ql[mf][ks], kh, acc[mf][nf], 0, 0, 0);
            }
        }

    // ---- softmax in registers (row lives on 16 lanes sharing lg) ----
    float lsum[2][4];
#pragma unroll
    for (int mf = 0; mf < 2; ++mf)
#pragma unroll
        for (int r = 0; r < 4; ++r) {
            float m = acc[mf][0][r];
#pragma unroll
            for (int nf = 1; nf < 8; ++nf) m = fmaxf(m, acc[mf][nf][r]);
            m *= 0.125f;
#pragma unroll
            for (int off = 1; off < 16; off <<= 1) m = fmaxf(m, __shfl_xor(m, off));
            float s = 0.f;
#pragma unroll
            for (int nf = 0; nf < 8; ++nf) {
                float p = __expf(acc[mf][nf][r] * 0.125f - m);
                acc[mf][nf][r] = p;
                s += p;
            }
#pragma unroll
            for (int off = 1; off < 16; off <<= 1) s += __shfl_xor(s, off);
            lsum[mf][r] = s;
        }

    __syncthreads();   // all waves done reading K chunks -> reuse region for P

    // ---- X = P V (P via per-wave LDS transpose, split hi/lo) ----
    float* Pw = (float*)(void*)lds + wv * 1056;   // [32][33] f32, 4224 B/wave
    f32x4 x[2][4];
#pragma unroll
    for (int mf = 0; mf < 2; ++mf)
#pragma unroll
        for (int dc = 0; dc < 4; ++dc) x[mf][dc] = (f32x4){0.f,0.f,0.f,0.f};

#pragma unroll
    for (int ks = 0; ks < 4; ++ks) {
        // write this kstep's P slice (C-layout -> row-major [32][33])
#pragma unroll
        for (int mf = 0; mf < 2; ++mf)
#pragma unroll
            for (int nf2 = 0; nf2 < 2; ++nf2)
#pragma unroll
                for (int r = 0; r < 4; ++r)
                    Pw[(mf*16 + lg*4 + r) * 33 + nf2*16 + lr] = acc[mf][2*ks + nf2][r];
        // read back as A-fragments, split hi/lo
        s16x8 ph[2], pl[2];
#pragma unroll
        for (int mf = 0; mf < 2; ++mf)
#pragma unroll
            for (int j = 0; j < 8; ++j) {
                float f = Pw[(mf*16 + lr) * 33 + lg*8 + j];
                ushort hu = bf16_rtn(f);
                ph[mf][j] = (short)hu;
                pl[mf][j] = (short)bf16_rtn(f - __uint_as_float(((unsigned)hu) << 16));
            }
#pragma unroll
        for (int dc = 0; dc < 4; ++dc) {
            s16x8 vh = *(const s16x8*)&lds[16384 + (dc*4 + ks) * 512 + lane * 8];
            s16x8 vl = *(const s16x8*)&lds[24576 + (dc*4 + ks) * 512 + lane * 8];
#pragma unroll
            for (int mf = 0; mf < 2; ++mf) {
                x[mf][dc] = __builtin_amdgcn_mfma_f32_16x16x32_bf16(ph[mf], vh, x[mf][dc], 0, 0, 0);
                x[mf][dc] = __builtin_amdgcn_mfma_f32_16x16x32_bf16(ph[mf], vl, x[mf][dc], 0, 0, 0);
                x[mf][dc] = __builtin_amdgcn_mfma_f32_16x16x32_bf16(pl[mf], vh, x[mf][dc], 0, 0, 0);
            }
        }
    }

    // ---- epilogue: normalize by 1/l and store ----
#pragma unroll
    for (int mf = 0; mf < 2; ++mf)
#pragma unroll
        for (int r = 0; r < 4; ++r) {
            float inv = 1.f / lsum[mf][r];
            float* op = x1 + ((size_t)(n*128 + wv*32 + mf*16 + lg*4 + r)) * D + h*64;
#pragma unroll
            for (int dc = 0; dc < 4; ++dc)
                op[dc*16 + lr] = x[mf][dc][r] * inv;
        }
}

// ---------------------------------------------------------------------------
// Attention 2: per (s,b), self-attention over A=16 with q=k=v, 8 heads.
// ---------------------------------------------------------------------------
__global__ __launch_bounds__(256) void attn2_kernel(const float* __restrict__ x1,
                                                    float* __restrict__ x2)
{
    __shared__ float Xs[16][516];
    __shared__ float Sc[8][16][16];
    int m = blockIdx.x;
    int s = m >> 4, b = m & 15;
    int t = threadIdx.x;
#pragma unroll
    for (int i = 0; i < 8; ++i) {
        int f4 = t + 256 * i;
        int a = f4 >> 7, d4 = f4 & 127;
        float4 vv = ld4(x1 + (((size_t)(a * 16 + b)) * 128 + s) * D + d4*4);
        *(float4*)&Xs[a][d4*4] = vv;
    }
    __syncthreads();
    {
        int h = t >> 5;
        int idx = t & 31;
        int r = idx >> 1;
        int jb = (idx & 1) * 8;
        float4 qv[16];
#pragma unroll
        for (int i = 0; i < 16; ++i) qv[i] = ld4(&Xs[r][h*64 + i*4]);
        for (int j = jb; j < jb + 8; ++j) {
            float sacc = 0.f;
#pragma unroll
            for (int i = 0; i < 16; ++i) {
                float4 kv = ld4(&Xs[j][h*64 + i*4]);
                sacc += qv[i].x*kv.x + qv[i].y*kv.y + qv[i].z*kv.z + qv[i].w*kv.w;
            }
            Sc[h][r][j] = sacc * 0.125f;
        }
    }
    __syncthreads();
    if (t < 128) {
        int h = t >> 4, r = t & 15;
        float* row = &Sc[h][r][0];
        float mx = row[0];
#pragma unroll
        for (int j = 1; j < 16; ++j) mx = fmaxf(mx, row[j]);
        float sum = 0.f;
#pragma unroll
        for (int j = 0; j < 16; ++j) { float e = expf(row[j] - mx); row[j] = e; sum += e; }
        float inv = 1.f / sum;
#pragma unroll
        for (int j = 0; j < 16; ++j) row[j] *= inv;
    }
    __syncthreads();
#pragma unroll
    for (int i = 0; i < 8; ++i) {
        int f4 = t + 256 * i;
        int a = f4 >> 7, d4 = f4 & 127;
        int h = d4 >> 4;
        float4 acc = {0,0,0,0};
#pragma unroll
        for (int j = 0; j < 16; ++j) {
            float wj = Sc[h][a][j];
            float4 vv = ld4(&Xs[j][d4*4]);
            acc.x += wj*vv.x; acc.y += wj*vv.y; acc.z += wj*vv.z; acc.w += wj*vv.w;
        }
        *(float4*)(x2 + (((size_t)(a * 16 + b)) * 128 + s) * D + d4*4) = acc;
    }
}

// ---------------------------------------------------------------------------
// Workspace (float offsets):
//  P0 [0)            66 MiB : Y / V / X1
//  P1 [17301504)     64 MiB : Q / X2
//  P2 [34078720)     64 MiB : K
//  WB [50855936)    0.6 MiB : window weights
//  Wh [51019776)    0.5 MiB : W hi (bf16)
//  Wl [51150848)    0.5 MiB : W lo (bf16)
// ---------------------------------------------------------------------------
extern "C" void kernel_launch(void* const* d_in, const int* in_sizes, int n_in,
                              void* d_out, int out_size, void* d_ws, size_t ws_size,
                              hipStream_t stream)
{
    const float* query = (const float*)d_in[0];
    const float* key   = (const float*)d_in[1];
    const float* value = (const float*)d_in[2];
    // d_in[3] = mask (unused)
    const float* padq  = (const float*)d_in[4];
    const float* padk  = (const float*)d_in[5];
    const float* Wq = (const float*)d_in[6];  const float* bq = (const float*)d_in[7];
    const float* Wk = (const float*)d_in[8];  const float* bk = (const float*)d_in[9];
    const float* Wv = (const float*)d_in[10]; const float* bv = (const float*)d_in[11];
    const float* Wo = (const float*)d_in[12]; const float* bo = (const float*)d_in[13];
    float* out = (float*)d_out;
    float* W   = (float*)d_ws;

    float* Y   = W;                         // P0
    float* Q   = W + 17301504;              // P1
    float* K   = W + 34078720;              // P2
    float* WB  = W + 50855936;
    ushort* Whi = (ushort*)(W + 51019776);
    ushort* Wlo = (ushort*)(W + 51150848);
    float* V   = Y;
    float* X1  = V;
    float* X2  = Q;

    dim3 blk(256);
    const int Mbr = NB * T132;              // 33792
    const int Mfull = 32768;                // NB * S

    // ---- q branch ----
    split_rows<<<128, blk, 0, stream>>>(Wq, nullptr, Whi, Wlo, 512, 0);
    gemm_mfma_fused<<<dim3(Mbr/128, 4), blk, 0, stream>>>(query, padq, Whi, Wlo, bq, Y, T132, 4);
    win_weights<<<8192, blk, 0, stream>>>(Y, WB);
    win_combine<<<8192, blk, 0, stream>>>(Y, WB, Q);
    // ---- k branch ----
    split_rows<<<128, blk, 0, stream>>>(Wk, nullptr, Whi, Wlo, 512, 0);
    gemm_mfma_fused<<<dim3(Mbr/128, 4), blk, 0, stream>>>(key, padk, Whi, Wlo, bk, Y, T132, 4);
    win_weights<<<8192, blk, 0, stream>>>(Y, WB);
    win_combine<<<8192, blk, 0, stream>>>(Y, WB, K);
    // ---- v projection (single dispatch; fp32 read, writes V = Y region) ----
    split_rows<<<128, blk, 0, stream>>>(Wv, nullptr, Whi, Wlo, 512, 0);
    gemm_mfma_fused<<<dim3(Mfull/128, 4), blk, 0, stream>>>(value, nullptr, Whi, Wlo, bv, V, 128, 0);
    // ---- attention over S (MFMA); X1 in place over V ----
    attn1_kernel<<<2048, blk, 0, stream>>>(Q, K, V, X1);
    // ---- attention over A ----
    attn2_kernel<<<2048, blk, 0, stream>>>(X1, X2);
    // ---- output projection (single dispatch) ----
    split_rows<<<128, blk, 0, stream>>>(Wo, nullptr, Whi, Wlo, 512, 0);
    gemm_mfma_fused<<<dim3(Mfull/128, 4), blk, 0, stream>>>(X2, nullptr, Whi, Wlo, bo, out, 128, 0);
}

// Round 6
// 768.748 us; speedup vs baseline: 1.0270x; 1.0270x over previous
//
#include <hip/hip_runtime.h>
#include <math.h>

#define D 512
#define S 128
#define NB 256   // N = A*B
#define T132 132 // S + L - 1

typedef short s16x8 __attribute__((ext_vector_type(8)));   // 8 bf16 (4 VGPRs)
typedef float f32x4 __attribute__((ext_vector_type(4)));
typedef unsigned short ushort;

static inline __device__ float4 ld4(const float* p) { return *(const float4*)p; }
static inline __device__ float4 ld4s(const float* p) { return *(const float4*)p; }
static inline __device__ float2 ld2s(const float* p) { return *(const float2*)p; }

// async global->LDS, 16B per lane; lp must be wave-uniform base, lane l lands at lp + 16*l
#define GLOAD_LDS16(gp, lp) __builtin_amdgcn_global_load_lds( \
    (const __attribute__((address_space(1))) unsigned int*)(const void*)(gp), \
    (__attribute__((address_space(3))) unsigned int*)(void*)(lp), 16, 0, 0)

static inline __device__ ushort bf16_rtn(float f) {
    unsigned u = __float_as_uint(f);
    unsigned r = u + 0x7FFFu + ((u >> 16) & 1u);
    return (ushort)(r >> 16);
}

// v_cvt_pk_bf16_f32: src0 -> low 16, src1 -> high 16 (pk family convention)
static inline __device__ unsigned pk_bf16(float a, float b) {
    unsigned r;
    asm("v_cvt_pk_bf16_f32 %0, %1, %2" : "=v"(r) : "v"(a), "v"(b));
    return r;
}

// 8 fp32 -> hi/lo bf16 fragments (RNE hi, RNE residual lo); ~24 VALU ops.
static inline __device__ void split_frag(float4 a0, float4 a1, s16x8& h, s16x8& l) {
    float f[8] = {a0.x,a0.y,a0.z,a0.w,a1.x,a1.y,a1.z,a1.w};
    union U { unsigned u[4]; s16x8 v; } hu, lu;
#pragma unroll
    for (int p = 0; p < 4; ++p) {
        unsigned u = pk_bf16(f[2*p], f[2*p+1]);
        float h0 = __uint_as_float(u << 16);
        float h1 = __uint_as_float(u & 0xffff0000u);
        hu.u[p] = u;
        lu.u[p] = pk_bf16(f[2*p] - h0, f[2*p+1] - h1);
    }
    h = hu.v;
    l = lu.v;
}

// ---------------------------------------------------------------------------
// Split fp32 rows into bf16 hi/lo (now only used for the 512x512 weights).
// grid.x = rows/4, block 256.
// ---------------------------------------------------------------------------
__global__ __launch_bounds__(256) void split_rows(
    const float* __restrict__ x, const float* __restrict__ pad,
    ushort* __restrict__ hi, ushort* __restrict__ lo,
    int rowsPerN, int padRows)
{
    int id  = blockIdx.x * 256 + threadIdx.x;
    int row = id >> 6, c8 = (id & 63) * 8;
    int n = row / rowsPerN, r = row - n * rowsPerN;
    const float* src = (r < padRows)
        ? (pad + ((size_t)(n * padRows + r)) * D + c8)
        : (x   + ((size_t)(n * (rowsPerN - padRows) + (r - padRows))) * D + c8);
    float4 f0 = ld4(src), f1 = ld4(src + 4);
    float v[8] = {f0.x,f0.y,f0.z,f0.w,f1.x,f1.y,f1.z,f1.w};
    ushort h[8], l[8];
#pragma unroll
    for (int i = 0; i < 8; ++i) {
        h[i] = bf16_rtn(v[i]);
        float hf = __uint_as_float(((unsigned)h[i]) << 16);
        l[i] = bf16_rtn(v[i] - hf);
    }
    size_t o = (size_t)row * D + c8;
#pragma unroll
    for (int i = 0; i < 4; ++i) {
        ((ushort2*)(hi + o))[i] = make_ushort2(h[2*i], h[2*i+1]);
        ((ushort2*)(lo + o))[i] = make_ushort2(l[2*i], l[2*i+1]);
    }
}

// ---------------------------------------------------------------------------
// Fused split-bf16 MFMA GEMM: out[m][o] = sum_d A[m][d]*W[o][d] + bias[o].
// A is fp32 (optional per-n leading pad rows); staged fp32 via
// global_load_lds, split to bf16 hi/lo in-kernel (v_cvt_pk_bf16_f32) at
// fragment-read time. W pre-split bf16 hi/lo. 3 MFMA terms: hh + hl + lh.
// Tile 128x128, BK=32, **512 thr = 8 waves (4x2)**, each wave 32x64 via
// 2x4 mfma_f32_16x16x32_bf16 -> acc = 32 AGPRs/wave. With launch_bounds
// (512,4) the unified VGPR+AGPR stays <=128 -> 4 waves/SIMD -> 16 waves/CU
// (2 blocks/CU), double the 4-wave version's residency. Proven 2-barrier
// single-buffer loop (round-3 structure).
// LDS 32KB: A fp32 16 chunks [0,8192) ushorts, Whi [8192,12288),
// Wlo [12288,16384). Chunk = 64 lanes x 16B, fragment order
// (conflict-free ds_read_b128 / float4 reads).
// grid: (M/128, 4). M multiple of 128. K = N = 512.
// ---------------------------------------------------------------------------
__global__ __launch_bounds__(512, 4) void gemm_mfma_fused(
    const float* __restrict__ A, const float* __restrict__ pad,
    const ushort* __restrict__ Whi, const ushort* __restrict__ Wlo,
    const float* __restrict__ bias, float* __restrict__ out,
    int rowsPerN, int padRows)
{
    __shared__ ushort lds[16384];   // 32 KB
    const int t = threadIdx.x;
    const int wave = t >> 6, lane = t & 63;
    const int wm = wave >> 1, wn = wave & 1;   // wm 0..3 (32-row strip), wn 0..1 (64-col)
    const int blockRow = blockIdx.x * 128;
    const int blockCol = blockIdx.y * 128;
    const int lr = lane & 15, lg = lane >> 4;

    // ---- staging source pointers (computed once; +k0 per iteration) ----
    // waves 0..3: A rows, 2 subtiles each (sub = wave*2+st2), 4 loads/wave
    // waves 4,5: Whi chunks st 0..3 / 4..7; waves 6,7: Wlo same. 4 loads/wave.
    const float* rowPtr[2] = {nullptr, nullptr};
    const ushort* wPtr = nullptr;
    if (wave < 4) {
#pragma unroll
        for (int st2 = 0; st2 < 2; ++st2) {
            int row = blockRow + (wave * 2 + st2) * 16 + lr;
            const float* p;
            if (padRows > 0) {
                int n = row / rowsPerN, r = row - n * rowsPerN;
                p = (r < padRows)
                    ? pad + ((size_t)(n * padRows + r)) * D
                    : A   + ((size_t)(n * (rowsPerN - padRows) + (r - padRows))) * D;
            } else {
                p = A + (size_t)row * D;
            }
            rowPtr[st2] = p + lg * 8;
        }
    } else {
        const ushort* wsrc = (wave < 6) ? Whi : Wlo;
        wPtr = wsrc + (size_t)(blockCol + lr) * 512 + lg * 8;
    }
    const int wBase  = 8192 + ((wave - 4) >> 1) * 4096;  // Whi or Wlo region
    const int wStart = (wave & 1) * 4;                   // chunk range within it

    f32x4 acc[2][4];
#pragma unroll
    for (int i = 0; i < 2; ++i)
#pragma unroll
        for (int j = 0; j < 4; ++j) acc[i][j] = (f32x4){0.f,0.f,0.f,0.f};

    for (int k0 = 0; k0 < 512; k0 += 32) {
        __syncthreads();
        if (wave < 4) {
#pragma unroll
            for (int st2 = 0; st2 < 2; ++st2) {
                int sub = wave * 2 + st2;
                GLOAD_LDS16(rowPtr[st2] + k0,     &lds[(sub*2 + 0) * 512]);
                GLOAD_LDS16(rowPtr[st2] + k0 + 4, &lds[(sub*2 + 1) * 512]);
            }
        } else {
#pragma unroll
            for (int st = 0; st < 4; ++st)
                GLOAD_LDS16(wPtr + (size_t)(wStart + st) * 16 * 512 + k0,
                            &lds[wBase + (wStart + st) * 512]);
        }
        __syncthreads();

        const float* Af = (const float*)lds;
        s16x8 bh[4], bl[4];
#pragma unroll
        for (int j = 0; j < 4; ++j) {
            bh[j] = *(const s16x8*)&lds[ 8192 + (wn*4 + j) * 512 + lane * 8];
            bl[j] = *(const s16x8*)&lds[12288 + (wn*4 + j) * 512 + lane * 8];
        }
#pragma unroll
        for (int i = 0; i < 2; ++i) {
            int sub = wm * 2 + i;
            float4 a0 = *(const float4*)&Af[(sub*2 + 0) * 256 + lane * 4];
            float4 a1 = *(const float4*)&Af[(sub*2 + 1) * 256 + lane * 4];
            s16x8 ah, al;
            split_frag(a0, a1, ah, al);
#pragma unroll
            for (int j = 0; j < 4; ++j) {
                acc[i][j] = __builtin_amdgcn_mfma_f32_16x16x32_bf16(ah, bh[j], acc[i][j], 0, 0, 0);
                acc[i][j] = __builtin_amdgcn_mfma_f32_16x16x32_bf16(ah, bl[j], acc[i][j], 0, 0, 0);
                acc[i][j] = __builtin_amdgcn_mfma_f32_16x16x32_bf16(al, bh[j], acc[i][j], 0, 0, 0);
            }
        }
    }

    // epilogue: C/D layout col=lane&15, row=(lane>>4)*4+reg
#pragma unroll
    for (int j = 0; j < 4; ++j) {
        int col = blockCol + (wn * 4 + j) * 16 + lr;
        float bb = bias[col];
#pragma unroll
        for (int i = 0; i < 2; ++i) {
            int row0 = blockRow + (wm * 2 + i) * 16 + lg * 4;
#pragma unroll
            for (int r = 0; r < 4; ++r)
                out[(size_t)(row0 + r) * 512 + col] = acc[i][j][r] + bb;
        }
    }
}

// ---------------------------------------------------------------------------
// Window softmax weights: one wave per (n, s). y: [N][132][D].
// ---------------------------------------------------------------------------
__global__ __launch_bounds__(256) void win_weights(const float* __restrict__ y,
                                                   float* __restrict__ wbuf)
{
    int g = blockIdx.x * 256 + threadIdx.x;
    int wv = g >> 6, lane = g & 63;
    int n = wv >> 7, s = wv & 127;
    const float* base = y + ((size_t)(n * T132 + s)) * D;
    float4 c0 = ld4(base + 4*D + lane*4);
    float4 c1 = ld4(base + 4*D + 256 + lane*4);
    float sc[5];
#pragma unroll
    for (int j = 0; j < 5; ++j) {
        float4 a0 = ld4(base + j*D + lane*4);
        float4 a1 = ld4(base + j*D + 256 + lane*4);
        float p = c0.x*a0.x + c0.y*a0.y + c0.z*a0.z + c0.w*a0.w
                + c1.x*a1.x + c1.y*a1.y + c1.z*a1.z + c1.w*a1.w;
#pragma unroll
        for (int off = 1; off < 64; off <<= 1) p += __shfl_xor(p, off);
        sc[j] = p * 0.044194173824159216f;   // 1/sqrt(512)
    }
    if (lane == 0) {
        float mx = sc[0];
#pragma unroll
        for (int j = 1; j < 5; ++j) mx = fmaxf(mx, sc[j]);
        float e[5], sum = 0.f;
#pragma unroll
        for (int j = 0; j < 5; ++j) { e[j] = expf(sc[j] - mx); sum += e[j]; }
        float inv = 1.f / sum;
        float* wp = wbuf + ((size_t)(n * 128 + s)) * 5;
#pragma unroll
        for (int j = 0; j < 5; ++j) wp[j] = e[j] * inv;
    }
}

// ---------------------------------------------------------------------------
// Scrambled window combine (reference's reshape (S,L)->(L,S)):
// out[n,s2,:] = sum_{l2<5} w[n, f/5, f%5] * y[n, f/5 + f%5, :],  f = l2*128+s2
// ---------------------------------------------------------------------------
__global__ __launch_bounds__(256) void win_combine(const float* __restrict__ y,
                                                   const float* __restrict__ wbuf,
                                                   float* __restrict__ outq)
{
    int g = blockIdx.x * 256 + threadIdx.x;
    int wv = g >> 6, lane = g & 63;
    int n = wv >> 7, s2 = wv & 127;
    float4 a0 = {0,0,0,0}, a1 = {0,0,0,0};
#pragma unroll
    for (int l2 = 0; l2 < 5; ++l2) {
        int f = l2 * 128 + s2;
        int sidx = f / 5;
        int l = f - sidx * 5;
        float wt = wbuf[((size_t)(n * 128 + sidx)) * 5 + l];
        const float* r = y + ((size_t)(n * T132 + sidx + l)) * D;
        float4 v0 = ld4(r + lane*4), v1 = ld4(r + 256 + lane*4);
        a0.x += wt*v0.x; a0.y += wt*v0.y; a0.z += wt*v0.z; a0.w += wt*v0.w;
        a1.x += wt*v1.x; a1.y += wt*v1.y; a1.z += wt*v1.z; a1.w += wt*v1.w;
    }
    float* op = outq + ((size_t)(n * 128 + s2)) * D;
    *(float4*)(op + lane*4) = a0;
    *(float4*)(op + 256 + lane*4) = a1;
}

// ---------------------------------------------------------------------------
// Attention 1 (MFMA, split-bf16): one block per (n,h), 256 thr = 4 waves,
// each wave owns 32 q-rows. K and V^T staged in LDS as bf16 hi/lo fragment
// chunks. Q fragments global->reg. S = QK^T via 3-term split MFMA;
// softmax in registers; P via per-wave LDS transpose; X = PV split MFMA.
// LDS 64 KB -> 2 blocks/CU. x1 may alias v (V fully staged before write).
// ---------------------------------------------------------------------------
__global__ __launch_bounds__(256, 2) void attn1_kernel(const float* __restrict__ q,
                                                       const float* __restrict__ k,
                                                       const float* __restrict__ v,
                                                       float* __restrict__ x1)
{
    __shared__ ushort lds[32768];   // 64 KB

    const int n = blockIdx.x >> 3, h = blockIdx.x & 7;
    const int t = threadIdx.x;
    const int wv = t >> 6, lane = t & 63;
    const int lr = lane & 15, lg = lane >> 4;

    const float* qb = q + ((size_t)n * 128) * D + h * 64;
    const float* kb = k + ((size_t)n * 128) * D + h * 64;
    const float* vb = v + ((size_t)n * 128) * D + h * 64;

    // ---- stage K -> bf16 hi/lo chunks (rows = k-rows, cols = d) ----
#pragma unroll
    for (int it = 0; it < 4; ++it) {
        int slot = t + 256 * it;           // chunk*64 + lane-in-chunk
        int c = slot >> 6, cl = slot & 63;
        int row = (c >> 1) * 16 + (cl & 15);
        int kc  = (c & 1) * 32 + (cl >> 4) * 8;
        const float* src = kb + (size_t)row * D + kc;
        float4 f0 = ld4(src), f1 = ld4(src + 4);
        float vv[8] = {f0.x,f0.y,f0.z,f0.w,f1.x,f1.y,f1.z,f1.w};
        s16x8 hb, lb;
#pragma unroll
        for (int j = 0; j < 8; ++j) {
            ushort hu = bf16_rtn(vv[j]);
            hb[j] = (short)hu;
            lb[j] = (short)bf16_rtn(vv[j] - __uint_as_float(((unsigned)hu) << 16));
        }
        *(s16x8*)&lds[        c * 512 + cl * 8] = hb;
        *(s16x8*)&lds[ 8192 + c * 512 + cl * 8] = lb;
    }
    // ---- stage V^T -> bf16 hi/lo chunks (rows = d, cols = k-rows) ----
#pragma unroll
    for (int it = 0; it < 4; ++it) {
        int slot = t + 256 * it;
        int c = slot >> 6, cl = slot & 63;
        int d  = (c >> 2) * 16 + (cl & 15);
        int kr = (c & 3) * 32 + (cl >> 4) * 8;
        const float* src = vb + (size_t)kr * D + d;
        s16x8 hb, lb;
#pragma unroll
        for (int j = 0; j < 8; ++j) {
            float f = src[(size_t)j * D];
            ushort hu = bf16_rtn(f);
            hb[j] = (short)hu;
            lb[j] = (short)bf16_rtn(f - __uint_as_float(((unsigned)hu) << 16));
        }
        *(s16x8*)&lds[16384 + c * 512 + cl * 8] = hb;
        *(s16x8*)&lds[24576 + c * 512 + cl * 8] = lb;
    }
    // ---- Q fragments straight into registers ----
    s16x8 qh[2][2], ql[2][2];
#pragma unroll
    for (int mf = 0; mf < 2; ++mf)
#pragma unroll
        for (int ks = 0; ks < 2; ++ks) {
            const float* src = qb + (size_t)(wv*32 + mf*16 + lr) * D + ks*32 + lg*8;
            float4 f0 = ld4(src), f1 = ld4(src + 4);
            float vv[8] = {f0.x,f0.y,f0.z,f0.w,f1.x,f1.y,f1.z,f1.w};
#pragma unroll
            for (int j = 0; j < 8; ++j) {
                ushort hu = bf16_rtn(vv[j]);
                qh[mf][ks][j] = (short)hu;
                ql[mf][ks][j] = (short)bf16_rtn(vv[j] - __uint_as_float(((unsigned)hu) << 16));
            }
        }

    __syncthreads();

    // ---- S = Q K^T (3-term split): rows mf*16+lg*4+r, cols nf*16+lr ----
    f32x4 acc[2][8];
#pragma unroll
    for (int mf = 0; mf < 2; ++mf)
#pragma unroll
        for (int nf = 0; nf < 8; ++nf) acc[mf][nf] = (f32x4){0.f,0.f,0.f,0.f};

#pragma unroll
    for (int ks = 0; ks < 2; ++ks)
#pragma unroll
        for (int nf = 0; nf < 8; ++nf) {
            s16x8 kh = *(const s16x8*)&lds[       (nf*2 + ks) * 512 + lane * 8];
            s16x8 kl = *(const s16x8*)&lds[8192 + (nf*2 + ks) * 512 + lane * 8];
#pragma unroll
            for (int mf = 0; mf < 2; ++mf) {
                acc[mf][nf] = __builtin_amdgcn_mfma_f32_16x16x32_bf16(qh[mf][ks], kh, acc[mf][nf], 0, 0, 0);
                acc[mf][nf] = __builtin_amdgcn_mfma_f32_16x16x32_bf16(qh[mf][ks], kl, acc[mf][nf], 0, 0, 0);
                acc[mf][nf] = __builtin_amdgcn_mfma_f32_16x16x32_bf16(ql[mf][ks], kh, acc[mf][nf], 0, 0, 0);
            }
        }

    // ---- softmax in registers (row lives on 16 lanes sharing lg) ----
    float lsum[2][4];
#pragma unroll
    for (int mf = 0; mf < 2; ++mf)
#pragma unroll
        for (int r = 0; r < 4; ++r) {
            float m = acc[mf][0][r];
#pragma unroll
            for (int nf = 1; nf < 8; ++nf) m = fmaxf(m, acc[mf][nf][r]);
            m *= 0.125f;
#pragma unroll
            for (int off = 1; off < 16; off <<= 1) m = fmaxf(m, __shfl_xor(m, off));
            float s = 0.f;
#pragma unroll
            for (int nf = 0; nf < 8; ++nf) {
                float p = __expf(acc[mf][nf][r] * 0.125f - m);
                acc[mf][nf][r] = p;
                s += p;
            }
#pragma unroll
            for (int off = 1; off < 16; off <<= 1) s += __shfl_xor(s, off);
            lsum[mf][r] = s;
        }

    __syncthreads();   // all waves done reading K chunks -> reuse region for P

    // ---- X = P V (P via per-wave LDS transpose, split hi/lo) ----
    float* Pw = (float*)(void*)lds + wv * 1056;   // [32][33] f32, 4224 B/wave
    f32x4 x[2][4];
#pragma unroll
    for (int mf = 0; mf < 2; ++mf)
#pragma unroll
        for (int dc = 0; dc < 4; ++dc) x[mf][dc] = (f32x4){0.f,0.f,0.f,0.f};

#pragma unroll
    for (int ks = 0; ks < 4; ++ks) {
        // write this kstep's P slice (C-layout -> row-major [32][33])
#pragma unroll
        for (int mf = 0; mf < 2; ++mf)
#pragma unroll
            for (int nf2 = 0; nf2 < 2; ++nf2)
#pragma unroll
                for (int r = 0; r < 4; ++r)
                    Pw[(mf*16 + lg*4 + r) * 33 + nf2*16 + lr] = acc[mf][2*ks + nf2][r];
        // read back as A-fragments, split hi/lo
        s16x8 ph[2], pl[2];
#pragma unroll
        for (int mf = 0; mf < 2; ++mf)
#pragma unroll
            for (int j = 0; j < 8; ++j) {
                float f = Pw[(mf*16 + lr) * 33 + lg*8 + j];
                ushort hu = bf16_rtn(f);
                ph[mf][j] = (short)hu;
                pl[mf][j] = (short)bf16_rtn(f - __uint_as_float(((unsigned)hu) << 16));
            }
#pragma unroll
        for (int dc = 0; dc < 4; ++dc) {
            s16x8 vh = *(const s16x8*)&lds[16384 + (dc*4 + ks) * 512 + lane * 8];
            s16x8 vl = *(const s16x8*)&lds[24576 + (dc*4 + ks) * 512 + lane * 8];
#pragma unroll
            for (int mf = 0; mf < 2; ++mf) {
                x[mf][dc] = __builtin_amdgcn_mfma_f32_16x16x32_bf16(ph[mf], vh, x[mf][dc], 0, 0, 0);
                x[mf][dc] = __builtin_amdgcn_mfma_f32_16x16x32_bf16(ph[mf], vl, x[mf][dc], 0, 0, 0);
                x[mf][dc] = __builtin_amdgcn_mfma_f32_16x16x32_bf16(pl[mf], vh, x[mf][dc], 0, 0, 0);
            }
        }
    }

    // ---- epilogue: normalize by 1/l and store ----
#pragma unroll
    for (int mf = 0; mf < 2; ++mf)
#pragma unroll
        for (int r = 0; r < 4; ++r) {
            float inv = 1.f / lsum[mf][r];
            float* op = x1 + ((size_t)(n*128 + wv*32 + mf*16 + lg*4 + r)) * D + h*64;
#pragma unroll
            for (int dc = 0; dc < 4; ++dc)
                op[dc*16 + lr] = x[mf][dc][r] * inv;
        }
}

// ---------------------------------------------------------------------------
// Attention 2: per (s,b), self-attention over A=16 with q=k=v, 8 heads.
// ---------------------------------------------------------------------------
__global__ __launch_bounds__(256) void attn2_kernel(const float* __restrict__ x1,
                                                    float* __restrict__ x2)
{
    __shared__ float Xs[16][516];
    __shared__ float Sc[8][16][16];
    int m = blockIdx.x;
    int s = m >> 4, b = m & 15;
    int t = threadIdx.x;
#pragma unroll
    for (int i = 0; i < 8; ++i) {
        int f4 = t + 256 * i;
        int a = f4 >> 7, d4 = f4 & 127;
        float4 vv = ld4(x1 + (((size_t)(a * 16 + b)) * 128 + s) * D + d4*4);
        *(float4*)&Xs[a][d4*4] = vv;
    }
    __syncthreads();
    {
        int h = t >> 5;
        int idx = t & 31;
        int r = idx >> 1;
        int jb = (idx & 1) * 8;
        float4 qv[16];
#pragma unroll
        for (int i = 0; i < 16; ++i) qv[i] = ld4(&Xs[r][h*64 + i*4]);
        for (int j = jb; j < jb + 8; ++j) {
            float sacc = 0.f;
#pragma unroll
            for (int i = 0; i < 16; ++i) {
                float4 kv = ld4(&Xs[j][h*64 + i*4]);
                sacc += qv[i].x*kv.x + qv[i].y*kv.y + qv[i].z*kv.z + qv[i].w*kv.w;
            }
            Sc[h][r][j] = sacc * 0.125f;
        }
    }
    __syncthreads();
    if (t < 128) {
        int h = t >> 4, r = t & 15;
        float* row = &Sc[h][r][0];
        float mx = row[0];
#pragma unroll
        for (int j = 1; j < 16; ++j) mx = fmaxf(mx, row[j]);
        float sum = 0.f;
#pragma unroll
        for (int j = 0; j < 16; ++j) { float e = expf(row[j] - mx); row[j] = e; sum += e; }
        float inv = 1.f / sum;
#pragma unroll
        for (int j = 0; j < 16; ++j) row[j] *= inv;
    }
    __syncthreads();
#pragma unroll
    for (int i = 0; i < 8; ++i) {
        int f4 = t + 256 * i;
        int a = f4 >> 7, d4 = f4 & 127;
        int h = d4 >> 4;
        float4 acc = {0,0,0,0};
#pragma unroll
        for (int j = 0; j < 16; ++j) {
            float wj = Sc[h][a][j];
            float4 vv = ld4(&Xs[j][d4*4]);
            acc.x += wj*vv.x; acc.y += wj*vv.y; acc.z += wj*vv.z; acc.w += wj*vv.w;
        }
        *(float4*)(x2 + (((size_t)(a * 16 + b)) * 128 + s) * D + d4*4) = acc;
    }
}

// ---------------------------------------------------------------------------
// Workspace (float offsets):
//  P0 [0)            66 MiB : Y / V / X1
//  P1 [17301504)     64 MiB : Q / X2
//  P2 [34078720)     64 MiB : K
//  WB [50855936)    0.6 MiB : window weights
//  Wh [51019776)    0.5 MiB : W hi (bf16)
//  Wl [51150848)    0.5 MiB : W lo (bf16)
// ---------------------------------------------------------------------------
extern "C" void kernel_launch(void* const* d_in, const int* in_sizes, int n_in,
                              void* d_out, int out_size, void* d_ws, size_t ws_size,
                              hipStream_t stream)
{
    const float* query = (const float*)d_in[0];
    const float* key   = (const float*)d_in[1];
    const float* value = (const float*)d_in[2];
    // d_in[3] = mask (unused)
    const float* padq  = (const float*)d_in[4];
    const float* padk  = (const float*)d_in[5];
    const float* Wq = (const float*)d_in[6];  const float* bq = (const float*)d_in[7];
    const float* Wk = (const float*)d_in[8];  const float* bk = (const float*)d_in[9];
    const float* Wv = (const float*)d_in[10]; const float* bv = (const float*)d_in[11];
    const float* Wo = (const float*)d_in[12]; const float* bo = (const float*)d_in[13];
    float* out = (float*)d_out;
    float* W   = (float*)d_ws;

    float* Y   = W;                         // P0
    float* Q   = W + 17301504;              // P1
    float* K   = W + 34078720;              // P2
    float* WB  = W + 50855936;
    ushort* Whi = (ushort*)(W + 51019776);
    ushort* Wlo = (ushort*)(W + 51150848);
    float* V   = Y;
    float* X1  = V;
    float* X2  = Q;

    dim3 blk(256);
    dim3 blkG(512);
    const int Mbr = NB * T132;              // 33792
    const int Mfull = 32768;                // NB * S

    // ---- q branch ----
    split_rows<<<128, blk, 0, stream>>>(Wq, nullptr, Whi, Wlo, 512, 0);
    gemm_mfma_fused<<<dim3(Mbr/128, 4), blkG, 0, stream>>>(query, padq, Whi, Wlo, bq, Y, T132, 4);
    win_weights<<<8192, blk, 0, stream>>>(Y, WB);
    win_combine<<<8192, blk, 0, stream>>>(Y, WB, Q);
    // ---- k branch ----
    split_rows<<<128, blk, 0, stream>>>(Wk, nullptr, Whi, Wlo, 512, 0);
    gemm_mfma_fused<<<dim3(Mbr/128, 4), blkG, 0, stream>>>(key, padk, Whi, Wlo, bk, Y, T132, 4);
    win_weights<<<8192, blk, 0, stream>>>(Y, WB);
    win_combine<<<8192, blk, 0, stream>>>(Y, WB, K);
    // ---- v projection (single dispatch; fp32 read, writes V = Y region) ----
    split_rows<<<128, blk, 0, stream>>>(Wv, nullptr, Whi, Wlo, 512, 0);
    gemm_mfma_fused<<<dim3(Mfull/128, 4), blkG, 0, stream>>>(value, nullptr, Whi, Wlo, bv, V, 128, 0);
    // ---- attention over S (MFMA); X1 in place over V ----
    attn1_kernel<<<2048, blk, 0, stream>>>(Q, K, V, X1);
    // ---- attention over A ----
    attn2_kernel<<<2048, blk, 0, stream>>>(X1, X2);
    // ---- output projection (single dispatch) ----
    split_rows<<<128, blk, 0, stream>>>(Wo, nullptr, Whi, Wlo, 512, 0);
    gemm_mfma_fused<<<dim3(Mfull/128, 4), blkG, 0, stream>>>(X2, nullptr, Whi, Wlo, bo, out, 128, 0);
}